// Round 2
// baseline (282.113 us; speedup 1.0000x reference)
//
#include <hip/hip_runtime.h>
#include <hip/hip_bf16.h>
#include <math.h>

#define B_   16
#define INP  32
#define OUP  64
#define HID  192
#define H_   96
#define W_   96
#define HW_  (H_*W_)   // 9216
#define TC   48
#define TR   48

__device__ __forceinline__ float relu6f(float v) { return fminf(fmaxf(v, 0.f), 6.f); }

// ---------------------------------------------------------------------------
// K1: 1x1 conv (32->192) + BN1 + ReLU6 -> y ; fused SE-weighted 16x16 pooling
// block = one (b, pool-cell); 256 threads = 16x16 pixels
// ---------------------------------------------------------------------------
__global__ __launch_bounds__(256) void k1_conv1_pool(
    const float* __restrict__ x, const float* __restrict__ w1,
    const float* __restrict__ g1, const float* __restrict__ b1,
    const float* __restrict__ m1, const float* __restrict__ v1,
    const float* __restrict__ se_w, const float* __restrict__ se_b,
    float* __restrict__ y, float* __restrict__ se6)
{
    __shared__ __align__(16) float wl[HID*INP];
    __shared__ float s1[HID], t1[HID], sew[HID];
    __shared__ float red[256];
    const int tid = threadIdx.x;
    const int bx  = blockIdx.x;           // b*36 + cell
    const int b   = bx / 36, cell = bx % 36;
    const int br  = cell / 6, bc = cell % 6;

    for (int k = tid; k < HID*INP; k += 256) wl[k] = w1[k];
    for (int o = tid; o < HID; o += 256) {
        float sc = g1[o] * rsqrtf(v1[o] + 1e-5f);
        s1[o] = sc; t1[o] = b1[o] - m1[o]*sc; sew[o] = se_w[o];
    }
    __syncthreads();

    const int ty = tid >> 4, tx = tid & 15;
    const int h = br*16 + ty, w = bc*16 + tx;
    const int sp = h*W_ + w;

    float xr[INP];
    #pragma unroll
    for (int i = 0; i < INP; ++i) xr[i] = x[(size_t)(b*INP + i)*HW_ + sp];

    float tsum = 0.f;
    float* yb = y + (size_t)b*HID*HW_ + sp;
    for (int o = 0; o < HID; ++o) {
        float acc = 0.f;
        const float4* wv = (const float4*)&wl[o*INP];
        #pragma unroll
        for (int i4 = 0; i4 < INP/4; ++i4) {
            float4 ww = wv[i4];
            acc += ww.x*xr[i4*4+0] + ww.y*xr[i4*4+1]
                 + ww.z*xr[i4*4+2] + ww.w*xr[i4*4+3];
        }
        float yv = relu6f(acc*s1[o] + t1[o]);
        yb[(size_t)o*HW_] = yv;
        tsum += sew[o]*yv;
    }

    red[tid] = tsum; __syncthreads();
    for (int s = 128; s > 0; s >>= 1) {
        if (tid < s) red[tid] += red[tid+s];
        __syncthreads();
    }
    if (tid == 0) {
        float logit = red[0]*(1.f/256.f) + se_b[0];
        se6[bx] = 1.f/(1.f + expf(-logit));
    }
}

// ---------------------------------------------------------------------------
// K3: per (b,h) row — bilinear SE upsample, cumsum xx, searchsorted ->
//     iW (gather idx), AW=se0*(1-t), BW=se1*t, mm (warped se)
// ---------------------------------------------------------------------------
__global__ __launch_bounds__(128) void k3_rows(
    const float* __restrict__ se6,
    int* __restrict__ iW, float* __restrict__ AW, float* __restrict__ BW,
    float* __restrict__ mm)
{
    const int bx = blockIdx.x;            // b*H_ + h
    const int b = bx / H_, h = bx % H_;
    const int tid = threadIdx.x;
    __shared__ float ysr[W_];
    __shared__ float xxl[W_];

    const float* s6 = se6 + b*36;
    float ch = h * (5.0f/95.0f);
    int r0 = (int)floorf(ch); r0 = min(max(r0, 0), 4);
    float fr = ch - (float)r0;

    if (tid < W_) {
        float cw = tid * (5.0f/95.0f);
        int c0 = (int)floorf(cw); c0 = min(max(c0, 0), 4);
        float fc = cw - (float)c0;
        float v00 = s6[r0*6 + c0],     v01 = s6[r0*6 + c0 + 1];
        float v10 = s6[(r0+1)*6 + c0], v11 = s6[(r0+1)*6 + c0 + 1];
        float ra = v00*(1.f-fr) + v10*fr;     // interp rows first (ref order)
        float rb = v01*(1.f-fr) + v11*fr;
        ysr[tid] = ra*(1.f-fc) + rb*fc;
    }
    __syncthreads();
    if (tid == 0) {
        float rs = 0.f;
        for (int w = 0; w < W_; ++w) rs += ysr[w] + 0.001f;
        float scale = (W_*0.5f)/rs;
        float cum = 0.f;
        for (int w = 0; w < W_; ++w) { cum += scale*(ysr[w]+0.001f) + 0.5f; xxl[w] = cum; }
    }
    __syncthreads();
    if (tid < TC) {
        float cq = tid * 2.0f;
        int cnt = 0;
        for (int w = 0; w < W_; ++w) cnt += (xxl[w] < cq) ? 1 : 0;
        int i = min(max(cnt - 1, 0), W_ - 2);
        float x0 = xxl[i], x1 = xxl[i+1];
        float t = (cq - x0)/(x1 - x0);
        int idx = bx*TC + tid;
        float s0 = ysr[i], s1v = ysr[i+1];
        iW[idx] = i;
        AW[idx] = s0*(1.f - t);
        BW[idx] = s1v*t;
        mm[idx] = s0 + (s1v - s0)*t;
    }
}

// ---------------------------------------------------------------------------
// K4: horizontal warp of y (with SE gate folded into A/B): mf[b,c,h,j]
// ---------------------------------------------------------------------------
__global__ __launch_bounds__(256) void k4_mf(
    const float* __restrict__ y, const int* __restrict__ iW,
    const float* __restrict__ AW, const float* __restrict__ BW,
    float* __restrict__ mf)
{
    const int idx = blockIdx.x*256 + threadIdx.x;   // B*HID*H_*TC
    const int j = idx % TC;
    const int h = (idx / TC) % H_;
    const int c = (idx / (TC*H_)) % HID;
    const int b =  idx / (TC*H_*HID);
    const int rid = (b*H_ + h)*TC + j;
    const int i = iW[rid];
    const float* yr = y + ((size_t)(b*HID + c)*H_ + h)*W_;
    mf[idx] = yr[i]*AW[rid] + yr[i+1]*BW[rid];
}

// ---------------------------------------------------------------------------
// K5: per (b,j) column — cumsum yy over h, searchsorted -> i2T/A2T/B2T [b][r][j]
// ---------------------------------------------------------------------------
__global__ __launch_bounds__(128) void k5_cols(
    const float* __restrict__ mm, int* __restrict__ i2T,
    float* __restrict__ A2T, float* __restrict__ B2T)
{
    const int bx = blockIdx.x;            // b*TC + j
    const int b = bx / TC, j = bx % TC;
    const int tid = threadIdx.x;
    __shared__ float cmv[H_], yyl[H_];

    if (tid < H_) cmv[tid] = mm[(b*H_ + tid)*TC + j] + 0.001f;
    __syncthreads();
    if (tid == 0) {
        float cs = 0.f;
        for (int hh = 0; hh < H_; ++hh) cs += cmv[hh];
        float scale = (H_*0.5f)/cs;
        float cum = 0.f;
        for (int hh = 0; hh < H_; ++hh) { cum += scale*cmv[hh] + 0.5f; yyl[hh] = cum; }
    }
    __syncthreads();
    if (tid < TR) {
        float rq = tid * 2.0f;
        int cnt = 0;
        for (int hh = 0; hh < H_; ++hh) cnt += (yyl[hh] < rq) ? 1 : 0;
        int i2 = min(max(cnt - 1, 0), H_ - 2);
        float p0 = yyl[i2], p1 = yyl[i2+1];
        float t2 = (rq - p0)/(p1 - p0);
        int idx = (b*TR + tid)*TC + j;    // transposed: [b][r][j] for K6 coalescing
        i2T[idx] = i2; A2T[idx] = 1.f - t2; B2T[idx] = t2;
    }
}

// ---------------------------------------------------------------------------
// K6: vertical warp of mf -> ff[b,c,r,j]
// ---------------------------------------------------------------------------
__global__ __launch_bounds__(256) void k6_ff(
    const float* __restrict__ mf, const int* __restrict__ i2T,
    const float* __restrict__ A2T, const float* __restrict__ B2T,
    float* __restrict__ ff)
{
    const int idx = blockIdx.x*256 + threadIdx.x;   // B*HID*TR*TC
    const int j = idx % TC;
    const int r = (idx / TC) % TR;
    const int c = (idx / (TC*TR)) % HID;
    const int b =  idx / (TC*TR*HID);
    const int rid = (b*TR + r)*TC + j;
    const int i2 = i2T[rid];
    const float* mfc = mf + (size_t)(b*HID + c)*H_*TC;
    ff[idx] = mfc[i2*TC + j]*A2T[rid] + mfc[(i2+1)*TC + j]*B2T[rid];
}

// ---------------------------------------------------------------------------
// K7: depthwise 3x3 SAME + BN2 + ReLU6 ; block = one (b,c) 48x48 plane
// ---------------------------------------------------------------------------
__global__ __launch_bounds__(256) void k7_dw(
    const float* __restrict__ ff, const float* __restrict__ wdw,
    const float* __restrict__ g2, const float* __restrict__ b2,
    const float* __restrict__ m2, const float* __restrict__ v2,
    float* __restrict__ z1)
{
    const int bcid = blockIdx.x;          // b*HID + c
    const int c = bcid % HID;
    const int tid = threadIdx.x;
    __shared__ float pl[TR*TC];           // 2304 floats
    const float* fp = ff + (size_t)bcid*TR*TC;
    for (int k = tid; k < TR*TC; k += 256) pl[k] = fp[k];
    float wk[9];
    #pragma unroll
    for (int k = 0; k < 9; ++k) wk[k] = wdw[c*9 + k];
    float sc = g2[c]*rsqrtf(v2[c] + 1e-5f);
    float sh = b2[c] - m2[c]*sc;
    __syncthreads();
    float* zp = z1 + (size_t)bcid*TR*TC;
    for (int p = 0; p < 9; ++p) {
        int pix = tid + p*256;
        int r = pix / TC, j = pix % TC;
        float acc = 0.f;
        #pragma unroll
        for (int dr = -1; dr <= 1; ++dr)
            #pragma unroll
            for (int dj = -1; dj <= 1; ++dj) {
                int rr = r + dr, jj = j + dj;
                if (rr >= 0 && rr < TR && jj >= 0 && jj < TC)
                    acc += pl[rr*TC + jj]*wk[(dr+1)*3 + (dj+1)];
            }
        zp[pix] = relu6f(acc*sc + sh);
    }
}

// ---------------------------------------------------------------------------
// K8: 1x1 conv (192->64) + BN3 -> out ; 64 pixels x 4 o-chunks per block
// ---------------------------------------------------------------------------
__global__ __launch_bounds__(256) void k8_conv2(
    const float* __restrict__ z1, const float* __restrict__ w2,
    const float* __restrict__ g3, const float* __restrict__ b3,
    const float* __restrict__ m3, const float* __restrict__ v3,
    float* __restrict__ out)
{
    __shared__ __align__(16) float w2t[HID*OUP];   // 48 KiB, transposed [c][o]
    __shared__ float s3[OUP], t3[OUP];
    const int tid = threadIdx.x;
    for (int k = tid; k < HID*OUP; k += 256) {
        int o = k / HID, c = k % HID;
        w2t[c*OUP + o] = w2[k];
    }
    if (tid < OUP) {
        float sc = g3[tid]*rsqrtf(v3[tid] + 1e-5f);
        s3[tid] = sc; t3[tid] = b3[tid] - m3[tid]*sc;
    }
    __syncthreads();

    const int pg  = tid & 63;
    const int oc  = tid >> 6;                 // o-chunk 0..3 (16 outputs each)
    const int pix = blockIdx.x*64 + pg;       // 0 .. B*TR*TC-1
    const int b   = pix / (TR*TC);
    const int sp  = pix % (TR*TC);

    float acc[16];
    #pragma unroll
    for (int o = 0; o < 16; ++o) acc[o] = 0.f;

    const float* zb = z1 + (size_t)b*HID*TR*TC + sp;
    for (int c = 0; c < HID; ++c) {
        float zv = zb[(size_t)c*TR*TC];
        const float4* wv = (const float4*)&w2t[c*OUP + oc*16];
        #pragma unroll
        for (int o4 = 0; o4 < 4; ++o4) {
            float4 ww = wv[o4];
            acc[o4*4+0] += zv*ww.x; acc[o4*4+1] += zv*ww.y;
            acc[o4*4+2] += zv*ww.z; acc[o4*4+3] += zv*ww.w;
        }
    }
    float* ob = out + (size_t)b*OUP*TR*TC + sp;
    #pragma unroll
    for (int o = 0; o < 16; ++o) {
        int oo = oc*16 + o;
        ob[(size_t)oo*TR*TC] = acc[o]*s3[oo] + t3[oo];
    }
}

// ---------------------------------------------------------------------------
extern "C" void kernel_launch(void* const* d_in, const int* in_sizes, int n_in,
                              void* d_out, int out_size, void* d_ws, size_t ws_size,
                              hipStream_t stream)
{
    const float* x    = (const float*)d_in[0];
    const float* w1   = (const float*)d_in[1];
    const float* g1   = (const float*)d_in[2];
    const float* b1   = (const float*)d_in[3];
    const float* m1   = (const float*)d_in[4];
    const float* v1   = (const float*)d_in[5];
    const float* se_w = (const float*)d_in[6];
    const float* se_b = (const float*)d_in[7];
    const float* wdw  = (const float*)d_in[8];
    const float* g2   = (const float*)d_in[9];
    const float* b2   = (const float*)d_in[10];
    const float* m2   = (const float*)d_in[11];
    const float* v2   = (const float*)d_in[12];
    const float* w2   = (const float*)d_in[13];
    const float* g3   = (const float*)d_in[14];
    const float* b3   = (const float*)d_in[15];
    const float* m3   = (const float*)d_in[16];
    const float* v3   = (const float*)d_in[17];
    float* out = (float*)d_out;

    float* ws = (float*)d_ws;
    // workspace layout (floats); total 43,020,864 floats = 172.1 MB
    float* y    = ws;                      // 28,311,552 (B*HID*96*96)
    float* mf   = ws + 28311552;           // 14,155,776 (B*HID*96*48)
    float* se6  = ws + 42467328;           //        576
    int*   iW   = (int*)(ws + 42467904);   //     73,728
    float* AW   = ws + 42541632;           //     73,728
    float* BW   = ws + 42615360;           //     73,728
    float* mm   = ws + 42689088;           //     73,728
    int*   i2T  = (int*)(ws + 42762816);   //     36,864
    float* A2T  = ws + 42799680;           //     36,864
    float* B2T  = ws + 42836544;           //     36,864
    // y is dead after K4 -> alias ff and z1 into it
    float* ff   = y;                       //  7,077,888 (B*HID*48*48)
    float* z1   = y + 7077888;             //  7,077,888

    k1_conv1_pool<<<B_*36, 256, 0, stream>>>(x, w1, g1, b1, m1, v1, se_w, se_b, y, se6);
    k3_rows<<<B_*H_, 128, 0, stream>>>(se6, iW, AW, BW, mm);
    k4_mf<<<(B_*HID*H_*TC)/256, 256, 0, stream>>>(y, iW, AW, BW, mf);
    k5_cols<<<B_*TC, 128, 0, stream>>>(mm, i2T, A2T, B2T);
    k6_ff<<<(B_*HID*TR*TC)/256, 256, 0, stream>>>(mf, i2T, A2T, B2T, ff);
    k7_dw<<<B_*HID, 256, 0, stream>>>(ff, wdw, g2, b2, m2, v2, z1);
    k8_conv2<<<(B_*TR*TC)/64, 256, 0, stream>>>(z1, w2, g3, b3, m3, v3, out);
}

// Round 3
// 263.070 us; speedup vs baseline: 1.0724x; 1.0724x over previous
//
#include <hip/hip_runtime.h>
#include <hip/hip_bf16.h>
#include <math.h>

#define B_   16
#define INP  32
#define OUP  64
#define HID  192
#define H_   96
#define W_   96
#define HW_  (H_*W_)   // 9216
#define TC   48
#define TR   48

__device__ __forceinline__ float relu6f(float v) { return fminf(fmaxf(v, 0.f), 6.f); }

// ---------------------------------------------------------------------------
// K0: prep — fold BN1 into w1s[o][i], t1[o]; BN3 into w2t[c][o], t3[o]
// ---------------------------------------------------------------------------
__global__ __launch_bounds__(256) void k0_prep(
    const float* __restrict__ w1, const float* __restrict__ g1,
    const float* __restrict__ b1, const float* __restrict__ m1,
    const float* __restrict__ v1,
    const float* __restrict__ w2, const float* __restrict__ g3,
    const float* __restrict__ b3, const float* __restrict__ m3,
    const float* __restrict__ v3,
    float* __restrict__ w1s, float* __restrict__ t1,
    float* __restrict__ w2t, float* __restrict__ t3)
{
    const int idx = blockIdx.x*256 + threadIdx.x;
    if (idx < HID*INP) {                       // w1s
        int o = idx / INP;
        w1s[idx] = w1[idx] * g1[o]*rsqrtf(v1[o] + 1e-5f);
    } else if (idx < HID*INP + HID) {          // t1
        int o = idx - HID*INP;
        float sc = g1[o]*rsqrtf(v1[o] + 1e-5f);
        t1[o] = b1[o] - m1[o]*sc;
    } else if (idx < HID*INP + HID + HID*OUP) {// w2t (transposed, BN3-scaled)
        int k = idx - (HID*INP + HID);
        int c = k / OUP, o = k % OUP;
        w2t[k] = w2[o*HID + c] * g3[o]*rsqrtf(v3[o] + 1e-5f);
    } else if (idx < HID*INP + HID + HID*OUP + OUP) { // t3
        int o = idx - (HID*INP + HID + HID*OUP);
        float sc = g3[o]*rsqrtf(v3[o] + 1e-5f);
        t3[o] = b3[o] - m3[o]*sc;
    }
}

// ---------------------------------------------------------------------------
// K1: 1x1 conv (32->192) + BN1 + ReLU6 -> y ; SE-weighted partial pooling.
// block = (b, pool-cell, channel-group of 48); 256 threads = 16x16 pixels.
// Weights via wave-uniform scalar loads (no LDS staging).
// ---------------------------------------------------------------------------
__global__ __launch_bounds__(256) void k1_conv1(
    const float* __restrict__ x, const float* __restrict__ w1s,
    const float* __restrict__ t1, const float* __restrict__ se_w,
    float* __restrict__ y, float* __restrict__ se_part)
{
    __shared__ float red[256];
    const int tid = threadIdx.x;
    const int bx  = blockIdx.x;              // b*144 + cell*4 + grp
    const int b   = bx / 144;
    const int rem = bx % 144;
    const int cell = rem >> 2, grp = rem & 3;
    const int br = cell / 6, bc = cell % 6;

    const int ty = tid >> 4, tx = tid & 15;
    const int h = br*16 + ty, w = bc*16 + tx;
    const int sp = h*W_ + w;

    float xr[INP];
    #pragma unroll
    for (int i = 0; i < INP; ++i) xr[i] = x[(size_t)(b*INP + i)*HW_ + sp];

    const int o0 = grp*48;
    float tsum = 0.f;
    float* yb = y + ((size_t)b*HID + o0)*HW_ + sp;
    const float* t1g = t1 + o0;
    const float* swg = se_w + o0;
    for (int oo = 0; oo < 48; ++oo) {
        const float4* wv = (const float4*)(w1s + (size_t)(o0 + oo)*INP);
        float a0 = 0.f, a1 = 0.f, a2 = 0.f, a3 = 0.f;
        #pragma unroll
        for (int i4 = 0; i4 < 8; i4 += 4) {
            float4 p = wv[i4+0], q = wv[i4+1], r = wv[i4+2], s = wv[i4+3];
            a0 += p.x*xr[i4*4+0]  + p.y*xr[i4*4+1]  + p.z*xr[i4*4+2]  + p.w*xr[i4*4+3];
            a1 += q.x*xr[i4*4+4]  + q.y*xr[i4*4+5]  + q.z*xr[i4*4+6]  + q.w*xr[i4*4+7];
            a2 += r.x*xr[i4*4+8]  + r.y*xr[i4*4+9]  + r.z*xr[i4*4+10] + r.w*xr[i4*4+11];
            a3 += s.x*xr[i4*4+12] + s.y*xr[i4*4+13] + s.z*xr[i4*4+14] + s.w*xr[i4*4+15];
        }
        float yv = relu6f((a0+a1) + (a2+a3) + t1g[oo]);
        yb[(size_t)oo*HW_] = yv;
        tsum += swg[oo]*yv;
    }

    red[tid] = tsum; __syncthreads();
    for (int s = 128; s > 0; s >>= 1) {
        if (tid < s) red[tid] += red[tid+s];
        __syncthreads();
    }
    if (tid == 0) se_part[bx] = red[0];
}

// ---------------------------------------------------------------------------
// K2: se6[b,cell] = sigmoid(mean-pooled weighted sum + se_b)
// ---------------------------------------------------------------------------
__global__ __launch_bounds__(256) void k2_se(
    const float* __restrict__ se_part, const float* __restrict__ se_b,
    float* __restrict__ se6)
{
    const int id = blockIdx.x*256 + threadIdx.x;
    if (id < B_*36) {
        float s = se_part[id*4] + se_part[id*4+1] + se_part[id*4+2] + se_part[id*4+3];
        float logit = s*(1.f/256.f) + se_b[0];
        se6[id] = 1.f/(1.f + expf(-logit));
    }
}

// ---------------------------------------------------------------------------
// K3: per (b,h) row — bilinear SE upsample, cumsum xx, searchsorted ->
//     iW (gather idx), AW=se0*(1-t), BW=se1*t, mm (warped se)
// ---------------------------------------------------------------------------
__global__ __launch_bounds__(128) void k3_rows(
    const float* __restrict__ se6,
    int* __restrict__ iW, float* __restrict__ AW, float* __restrict__ BW,
    float* __restrict__ mm)
{
    const int bx = blockIdx.x;            // b*H_ + h
    const int b = bx / H_, h = bx % H_;
    const int tid = threadIdx.x;
    __shared__ float ysr[W_];
    __shared__ float xxl[W_];

    const float* s6 = se6 + b*36;
    float ch = h * (5.0f/95.0f);
    int r0 = (int)floorf(ch); r0 = min(max(r0, 0), 4);
    float fr = ch - (float)r0;

    if (tid < W_) {
        float cw = tid * (5.0f/95.0f);
        int c0 = (int)floorf(cw); c0 = min(max(c0, 0), 4);
        float fc = cw - (float)c0;
        float v00 = s6[r0*6 + c0],     v01 = s6[r0*6 + c0 + 1];
        float v10 = s6[(r0+1)*6 + c0], v11 = s6[(r0+1)*6 + c0 + 1];
        float ra = v00*(1.f-fr) + v10*fr;
        float rb = v01*(1.f-fr) + v11*fr;
        ysr[tid] = ra*(1.f-fc) + rb*fc;
    }
    __syncthreads();
    if (tid == 0) {
        float rs = 0.f;
        for (int w = 0; w < W_; ++w) rs += ysr[w] + 0.001f;
        float scale = (W_*0.5f)/rs;
        float cum = 0.f;
        for (int w = 0; w < W_; ++w) { cum += scale*(ysr[w]+0.001f) + 0.5f; xxl[w] = cum; }
    }
    __syncthreads();
    if (tid < TC) {
        float cq = tid * 2.0f;
        int cnt = 0;
        for (int w = 0; w < W_; ++w) cnt += (xxl[w] < cq) ? 1 : 0;
        int i = min(max(cnt - 1, 0), W_ - 2);
        float x0 = xxl[i], x1 = xxl[i+1];
        float t = (cq - x0)/(x1 - x0);
        int idx = bx*TC + tid;
        float s0 = ysr[i], s1v = ysr[i+1];
        iW[idx] = i;
        AW[idx] = s0*(1.f - t);
        BW[idx] = s1v*t;
        mm[idx] = s0 + (s1v - s0)*t;
    }
}

// ---------------------------------------------------------------------------
// K5: per (b,j) column — cumsum yy over h, searchsorted -> i2T/A2T/B2T [b][r][j]
// ---------------------------------------------------------------------------
__global__ __launch_bounds__(128) void k5_cols(
    const float* __restrict__ mm, int* __restrict__ i2T,
    float* __restrict__ A2T, float* __restrict__ B2T)
{
    const int bx = blockIdx.x;            // b*TC + j
    const int b = bx / TC, j = bx % TC;
    const int tid = threadIdx.x;
    __shared__ float cmv[H_], yyl[H_];

    if (tid < H_) cmv[tid] = mm[(b*H_ + tid)*TC + j] + 0.001f;
    __syncthreads();
    if (tid == 0) {
        float cs = 0.f;
        for (int hh = 0; hh < H_; ++hh) cs += cmv[hh];
        float scale = (H_*0.5f)/cs;
        float cum = 0.f;
        for (int hh = 0; hh < H_; ++hh) { cum += scale*cmv[hh] + 0.5f; yyl[hh] = cum; }
    }
    __syncthreads();
    if (tid < TR) {
        float rq = tid * 2.0f;
        int cnt = 0;
        for (int hh = 0; hh < H_; ++hh) cnt += (yyl[hh] < rq) ? 1 : 0;
        int i2 = min(max(cnt - 1, 0), H_ - 2);
        float p0 = yyl[i2], p1 = yyl[i2+1];
        float t2 = (rq - p0)/(p1 - p0);
        int idx = (b*TR + tid)*TC + j;
        i2T[idx] = i2; A2T[idx] = 1.f - t2; B2T[idx] = t2;
    }
}

// ---------------------------------------------------------------------------
// K4: FUSED horizontal warp + vertical warp + depthwise 3x3 + BN2 + ReLU6.
// block = one (b,c) plane; mf (96x48) and ff (48x48) live in LDS only.
// ---------------------------------------------------------------------------
__global__ __launch_bounds__(256) void k4_warp_dw(
    const float* __restrict__ y,
    const int* __restrict__ iW, const float* __restrict__ AW,
    const float* __restrict__ BW,
    const int* __restrict__ i2T, const float* __restrict__ A2T,
    const float* __restrict__ B2T,
    const float* __restrict__ wdw,
    const float* __restrict__ g2, const float* __restrict__ b2,
    const float* __restrict__ m2, const float* __restrict__ v2,
    float* __restrict__ z1)
{
    __shared__ float mfs[H_*TC];   // 18 KiB
    __shared__ float ffs[TR*TC];   //  9 KiB
    const int tid = threadIdx.x;
    const int b = blockIdx.x / HID;
    const int c = blockIdx.x % HID;

    const float* yp = y + (size_t)(b*HID + c)*HW_;
    const int rbase = b*H_*TC;

    // Phase A: horizontal warp (SE gate folded into AW/BW)
    for (int k = tid; k < H_*TC; k += 256) {
        int h = k / TC;
        int rid = rbase + k;
        int i = iW[rid];
        const float* yr = yp + h*W_;
        mfs[k] = yr[i]*AW[rid] + yr[i+1]*BW[rid];
    }
    __syncthreads();

    // Phase B: vertical warp
    const int r2base = b*TR*TC;
    for (int k = tid; k < TR*TC; k += 256) {
        int j = k % TC;
        int rid = r2base + k;
        int i2 = i2T[rid];
        ffs[k] = mfs[i2*TC + j]*A2T[rid] + mfs[(i2+1)*TC + j]*B2T[rid];
    }

    float wk[9];
    #pragma unroll
    for (int k = 0; k < 9; ++k) wk[k] = wdw[c*9 + k];
    float sc = g2[c]*rsqrtf(v2[c] + 1e-5f);
    float sh = b2[c] - m2[c]*sc;
    __syncthreads();

    // Phase C: depthwise 3x3 SAME + BN2 + ReLU6
    float* zp = z1 + (size_t)(b*HID + c)*TR*TC;
    for (int k = tid; k < TR*TC; k += 256) {
        int r = k / TC, j = k % TC;
        float acc = 0.f;
        #pragma unroll
        for (int dr = -1; dr <= 1; ++dr)
            #pragma unroll
            for (int dj = -1; dj <= 1; ++dj) {
                int rr = r + dr, jj = j + dj;
                if (rr >= 0 && rr < TR && jj >= 0 && jj < TC)
                    acc += ffs[rr*TC + jj]*wk[(dr+1)*3 + (dj+1)];
            }
        zp[k] = relu6f(acc*sc + sh);
    }
}

// ---------------------------------------------------------------------------
// K8: 1x1 conv (192->64) + BN3 -> out. 32 px x 8 o-chunks (8 outs each).
// w2t read straight from L2 (pre-transposed, BN-scaled) — no LDS.
// ---------------------------------------------------------------------------
__global__ __launch_bounds__(256) void k8_conv2(
    const float* __restrict__ z1, const float* __restrict__ w2t,
    const float* __restrict__ t3, float* __restrict__ out)
{
    const int tid = threadIdx.x;
    const int pl  = tid & 31;                // pixel lane
    const int oc  = tid >> 5;                // o-chunk 0..7
    const int pix = blockIdx.x*32 + pl;      // 0 .. B*TR*TC-1
    const int b   = pix / (TR*TC);
    const int sp  = pix % (TR*TC);

    float acc[8];
    #pragma unroll
    for (int o = 0; o < 8; ++o) acc[o] = 0.f;

    const float* zb = z1 + (size_t)b*HID*TR*TC + sp;
    const float* wb = w2t + oc*8;
    for (int c = 0; c < HID; ++c) {
        float zv = zb[(size_t)c*TR*TC];
        const float4* wv = (const float4*)(wb + c*OUP);
        float4 wa = wv[0], wb4 = wv[1];
        acc[0] += zv*wa.x;  acc[1] += zv*wa.y;
        acc[2] += zv*wa.z;  acc[3] += zv*wa.w;
        acc[4] += zv*wb4.x; acc[5] += zv*wb4.y;
        acc[6] += zv*wb4.z; acc[7] += zv*wb4.w;
    }
    float* ob = out + (size_t)b*OUP*TR*TC + sp;
    #pragma unroll
    for (int o = 0; o < 8; ++o) {
        int oo = oc*8 + o;
        ob[(size_t)oo*TR*TC] = acc[o] + t3[oo];
    }
}

// ---------------------------------------------------------------------------
extern "C" void kernel_launch(void* const* d_in, const int* in_sizes, int n_in,
                              void* d_out, int out_size, void* d_ws, size_t ws_size,
                              hipStream_t stream)
{
    const float* x    = (const float*)d_in[0];
    const float* w1   = (const float*)d_in[1];
    const float* g1   = (const float*)d_in[2];
    const float* b1   = (const float*)d_in[3];
    const float* m1   = (const float*)d_in[4];
    const float* v1   = (const float*)d_in[5];
    const float* se_w = (const float*)d_in[6];
    const float* se_b = (const float*)d_in[7];
    const float* wdw  = (const float*)d_in[8];
    const float* g2   = (const float*)d_in[9];
    const float* b2   = (const float*)d_in[10];
    const float* m2   = (const float*)d_in[11];
    const float* v2   = (const float*)d_in[12];
    const float* w2   = (const float*)d_in[13];
    const float* g3   = (const float*)d_in[14];
    const float* b3   = (const float*)d_in[15];
    const float* m3   = (const float*)d_in[16];
    const float* v3   = (const float*)d_in[17];
    float* out = (float*)d_out;

    float* ws = (float*)d_ws;
    // workspace layout (floats), total ~35.82M floats = 143.3 MB
    float* y       = ws;                       // 28,311,552
    float* z1      = ws + 28311552;            //  7,077,888
    float* se6     = ws + 35389440;            //        576
    int*   iW      = (int*)(ws + 35390016);    //     73,728
    float* AW      = ws + 35463744;            //     73,728
    float* BW      = ws + 35537472;            //     73,728
    float* mm      = ws + 35611200;            //     73,728
    int*   i2T     = (int*)(ws + 35684928);    //     36,864
    float* A2T     = ws + 35721792;            //     36,864
    float* B2T     = ws + 35758656;            //     36,864
    float* se_part = ws + 35795520;            //      2,304
    float* w1s     = ws + 35797824;            //      6,144
    float* t1      = ws + 35803968;            //        192
    float* w2t     = ws + 35804160;            //     12,288
    float* t3      = ws + 35816448;            //         64

    k0_prep<<<73, 256, 0, stream>>>(w1, g1, b1, m1, v1, w2, g3, b3, m3, v3,
                                    w1s, t1, w2t, t3);
    k1_conv1<<<B_*144, 256, 0, stream>>>(x, w1s, t1, se_w, y, se_part);
    k2_se<<<3, 256, 0, stream>>>(se_part, se_b, se6);
    k3_rows<<<B_*H_, 128, 0, stream>>>(se6, iW, AW, BW, mm);
    k5_cols<<<B_*TC, 128, 0, stream>>>(mm, i2T, A2T, B2T);
    k4_warp_dw<<<B_*HID, 256, 0, stream>>>(y, iW, AW, BW, i2T, A2T, B2T,
                                           wdw, g2, b2, m2, v2, z1);
    k8_conv2<<<(B_*TR*TC)/32, 256, 0, stream>>>(z1, w2t, t3, out);
}

// Round 4
// 239.120 us; speedup vs baseline: 1.1798x; 1.1002x over previous
//
#include <hip/hip_runtime.h>
#include <hip/hip_bf16.h>
#include <math.h>

#define B_   16
#define INP  32
#define OUP  64
#define HID  192
#define H_   96
#define W_   96
#define HW_  (H_*W_)   // 9216
#define TC   48
#define TR   48

__device__ __forceinline__ float relu6f(float v) { return fminf(fmaxf(v, 0.f), 6.f); }
__device__ __forceinline__ float bf2f(unsigned short u) {
    unsigned int x = ((unsigned int)u) << 16;
    return __uint_as_float(x);
}
__device__ __forceinline__ unsigned short f2bf(float f) {
    // round-to-nearest-even bf16
    unsigned int x = __float_as_uint(f);
    unsigned int lsb = (x >> 16) & 1u;
    x += 0x7fffu + lsb;
    return (unsigned short)(x >> 16);
}

// ---------------------------------------------------------------------------
// K0: prep — fold BN1 into w1s[o][i], t1[o]; BN3 into w2t[c][o], t3[o]
// ---------------------------------------------------------------------------
__global__ __launch_bounds__(256) void k0_prep(
    const float* __restrict__ w1, const float* __restrict__ g1,
    const float* __restrict__ b1, const float* __restrict__ m1,
    const float* __restrict__ v1,
    const float* __restrict__ w2, const float* __restrict__ g3,
    const float* __restrict__ b3, const float* __restrict__ m3,
    const float* __restrict__ v3,
    float* __restrict__ w1s, float* __restrict__ t1,
    float* __restrict__ w2t, float* __restrict__ t3)
{
    const int idx = blockIdx.x*256 + threadIdx.x;
    if (idx < HID*INP) {
        int o = idx / INP;
        w1s[idx] = w1[idx] * g1[o]*rsqrtf(v1[o] + 1e-5f);
    } else if (idx < HID*INP + HID) {
        int o = idx - HID*INP;
        float sc = g1[o]*rsqrtf(v1[o] + 1e-5f);
        t1[o] = b1[o] - m1[o]*sc;
    } else if (idx < HID*INP + HID + HID*OUP) {
        int k = idx - (HID*INP + HID);
        int c = k / OUP, o = k % OUP;
        w2t[k] = w2[o*HID + c] * g3[o]*rsqrtf(v3[o] + 1e-5f);
    } else if (idx < HID*INP + HID + HID*OUP + OUP) {
        int o = idx - (HID*INP + HID + HID*OUP);
        float sc = g3[o]*rsqrtf(v3[o] + 1e-5f);
        t3[o] = b3[o] - m3[o]*sc;
    }
}

// ---------------------------------------------------------------------------
// K1: 1x1 conv (32->192) + BN1 + ReLU6 -> y (bf16) ; SE-weighted partials.
// block = (b, pool-cell, channel-group of 48); 256 threads = 16x16 pixels.
// ---------------------------------------------------------------------------
__global__ __launch_bounds__(256) void k1_conv1(
    const float* __restrict__ x, const float* __restrict__ w1s,
    const float* __restrict__ t1, const float* __restrict__ se_w,
    unsigned short* __restrict__ y, float* __restrict__ se_part)
{
    __shared__ float red[256];
    const int tid = threadIdx.x;
    const int bx  = blockIdx.x;              // b*144 + cell*4 + grp
    const int b   = bx / 144;
    const int rem = bx % 144;
    const int cell = rem >> 2, grp = rem & 3;
    const int br = cell / 6, bc = cell % 6;

    const int ty = tid >> 4, tx = tid & 15;
    const int h = br*16 + ty, w = bc*16 + tx;
    const int sp = h*W_ + w;

    float xr[INP];
    #pragma unroll
    for (int i = 0; i < INP; ++i) xr[i] = x[(size_t)(b*INP + i)*HW_ + sp];

    const int o0 = grp*48;
    float tsum = 0.f;
    unsigned short* yb = y + ((size_t)b*HID + o0)*HW_ + sp;
    const float* t1g = t1 + o0;
    const float* swg = se_w + o0;
    for (int oo = 0; oo < 48; ++oo) {
        const float4* wv = (const float4*)(w1s + (size_t)(o0 + oo)*INP);
        float a0 = 0.f, a1 = 0.f, a2 = 0.f, a3 = 0.f;
        #pragma unroll
        for (int i4 = 0; i4 < 8; i4 += 4) {
            float4 p = wv[i4+0], q = wv[i4+1], r = wv[i4+2], s = wv[i4+3];
            a0 += p.x*xr[i4*4+0]  + p.y*xr[i4*4+1]  + p.z*xr[i4*4+2]  + p.w*xr[i4*4+3];
            a1 += q.x*xr[i4*4+4]  + q.y*xr[i4*4+5]  + q.z*xr[i4*4+6]  + q.w*xr[i4*4+7];
            a2 += r.x*xr[i4*4+8]  + r.y*xr[i4*4+9]  + r.z*xr[i4*4+10] + r.w*xr[i4*4+11];
            a3 += s.x*xr[i4*4+12] + s.y*xr[i4*4+13] + s.z*xr[i4*4+14] + s.w*xr[i4*4+15];
        }
        float yv = relu6f((a0+a1) + (a2+a3) + t1g[oo]);
        yb[(size_t)oo*HW_] = f2bf(yv);
        tsum += swg[oo]*yv;     // pool on f32 value (matches ref)
    }

    red[tid] = tsum; __syncthreads();
    for (int s = 128; s > 0; s >>= 1) {
        if (tid < s) red[tid] += red[tid+s];
        __syncthreads();
    }
    if (tid == 0) se_part[bx] = red[0];
}

// ---------------------------------------------------------------------------
// K2: se6[b,cell] = sigmoid(mean-pooled weighted sum + se_b)
// ---------------------------------------------------------------------------
__global__ __launch_bounds__(256) void k2_se(
    const float* __restrict__ se_part, const float* __restrict__ se_b,
    float* __restrict__ se6)
{
    const int id = blockIdx.x*256 + threadIdx.x;
    if (id < B_*36) {
        float s = se_part[id*4] + se_part[id*4+1] + se_part[id*4+2] + se_part[id*4+3];
        float logit = s*(1.f/256.f) + se_b[0];
        se6[id] = 1.f/(1.f + expf(-logit));
    }
}

// ---------------------------------------------------------------------------
// K3: per (b,h) row — bilinear SE upsample, cumsum xx, searchsorted ->
//     iW, AW=se0*(1-t), BW=se1*t, mm (warped se)
// ---------------------------------------------------------------------------
__global__ __launch_bounds__(128) void k3_rows(
    const float* __restrict__ se6,
    int* __restrict__ iW, float* __restrict__ AW, float* __restrict__ BW,
    float* __restrict__ mm)
{
    const int bx = blockIdx.x;            // b*H_ + h
    const int b = bx / H_, h = bx % H_;
    const int tid = threadIdx.x;
    __shared__ float ysr[W_];
    __shared__ float xxl[W_];

    const float* s6 = se6 + b*36;
    float ch = h * (5.0f/95.0f);
    int r0 = (int)floorf(ch); r0 = min(max(r0, 0), 4);
    float fr = ch - (float)r0;

    if (tid < W_) {
        float cw = tid * (5.0f/95.0f);
        int c0 = (int)floorf(cw); c0 = min(max(c0, 0), 4);
        float fc = cw - (float)c0;
        float v00 = s6[r0*6 + c0],     v01 = s6[r0*6 + c0 + 1];
        float v10 = s6[(r0+1)*6 + c0], v11 = s6[(r0+1)*6 + c0 + 1];
        float ra = v00*(1.f-fr) + v10*fr;
        float rb = v01*(1.f-fr) + v11*fr;
        ysr[tid] = ra*(1.f-fc) + rb*fc;
    }
    __syncthreads();
    if (tid == 0) {
        float rs = 0.f;
        for (int w = 0; w < W_; ++w) rs += ysr[w] + 0.001f;
        float scale = (W_*0.5f)/rs;
        float cum = 0.f;
        for (int w = 0; w < W_; ++w) { cum += scale*(ysr[w]+0.001f) + 0.5f; xxl[w] = cum; }
    }
    __syncthreads();
    if (tid < TC) {
        float cq = tid * 2.0f;
        int cnt = 0;
        for (int w = 0; w < W_; ++w) cnt += (xxl[w] < cq) ? 1 : 0;
        int i = min(max(cnt - 1, 0), W_ - 2);
        float x0 = xxl[i], x1 = xxl[i+1];
        float t = (cq - x0)/(x1 - x0);
        int idx = bx*TC + tid;
        float s0 = ysr[i], s1v = ysr[i+1];
        iW[idx] = i;
        AW[idx] = s0*(1.f - t);
        BW[idx] = s1v*t;
        mm[idx] = s0 + (s1v - s0)*t;
    }
}

// ---------------------------------------------------------------------------
// K5: per (b,j) column — cumsum yy over h, searchsorted -> i2T/A2T/B2T [b][r][j]
// ---------------------------------------------------------------------------
__global__ __launch_bounds__(128) void k5_cols(
    const float* __restrict__ mm, int* __restrict__ i2T,
    float* __restrict__ A2T, float* __restrict__ B2T)
{
    const int bx = blockIdx.x;            // b*TC + j
    const int b = bx / TC, j = bx % TC;
    const int tid = threadIdx.x;
    __shared__ float cmv[H_], yyl[H_];

    if (tid < H_) cmv[tid] = mm[(b*H_ + tid)*TC + j] + 0.001f;
    __syncthreads();
    if (tid == 0) {
        float cs = 0.f;
        for (int hh = 0; hh < H_; ++hh) cs += cmv[hh];
        float scale = (H_*0.5f)/cs;
        float cum = 0.f;
        for (int hh = 0; hh < H_; ++hh) { cum += scale*cmv[hh] + 0.5f; yyl[hh] = cum; }
    }
    __syncthreads();
    if (tid < TR) {
        float rq = tid * 2.0f;
        int cnt = 0;
        for (int hh = 0; hh < H_; ++hh) cnt += (yyl[hh] < rq) ? 1 : 0;
        int i2 = min(max(cnt - 1, 0), H_ - 2);
        float p0 = yyl[i2], p1 = yyl[i2+1];
        float t2 = (rq - p0)/(p1 - p0);
        int idx = (b*TR + tid)*TC + j;
        i2T[idx] = i2; A2T[idx] = 1.f - t2; B2T[idx] = t2;
    }
}

// ---------------------------------------------------------------------------
// K4: FUSED horizontal warp + vertical warp + depthwise 3x3 + BN2 + ReLU6.
// block = one (b,c) plane; y-plane (bf16) staged in LDS with coalesced loads;
// mf (96x48) and ff (48x48) live in LDS only.
// ---------------------------------------------------------------------------
__global__ __launch_bounds__(256) void k4_warp_dw(
    const unsigned short* __restrict__ y,
    const int* __restrict__ iW, const float* __restrict__ AW,
    const float* __restrict__ BW,
    const int* __restrict__ i2T, const float* __restrict__ A2T,
    const float* __restrict__ B2T,
    const float* __restrict__ wdw,
    const float* __restrict__ g2, const float* __restrict__ b2,
    const float* __restrict__ m2, const float* __restrict__ v2,
    float* __restrict__ z1)
{
    __shared__ unsigned short ypl[HW_];  // 18 KiB (bf16 plane)
    __shared__ float mfs[H_*TC];         // 18 KiB
    __shared__ float ffs[TR*TC];         //  9 KiB
    const int tid = threadIdx.x;
    const int b = blockIdx.x / HID;
    const int c = blockIdx.x % HID;

    // coalesced stage of the 96x96 bf16 plane (1152 x uint4)
    const uint4* ysrc = (const uint4*)(y + (size_t)(b*HID + c)*HW_);
    uint4* ydst = (uint4*)ypl;
    for (int k = tid; k < HW_/8; k += 256) ydst[k] = ysrc[k];
    __syncthreads();

    const int rbase = b*H_*TC;
    // Phase A: horizontal warp (SE gate folded into AW/BW)
    for (int k = tid; k < H_*TC; k += 256) {
        int h = k / TC;
        int rid = rbase + k;
        int i = iW[rid];
        float y0 = bf2f(ypl[h*W_ + i]);
        float y1 = bf2f(ypl[h*W_ + i + 1]);
        mfs[k] = y0*AW[rid] + y1*BW[rid];
    }
    __syncthreads();

    // Phase B: vertical warp
    const int r2base = b*TR*TC;
    for (int k = tid; k < TR*TC; k += 256) {
        int j = k % TC;
        int rid = r2base + k;
        int i2 = i2T[rid];
        ffs[k] = mfs[i2*TC + j]*A2T[rid] + mfs[(i2+1)*TC + j]*B2T[rid];
    }

    float wk[9];
    #pragma unroll
    for (int k = 0; k < 9; ++k) wk[k] = wdw[c*9 + k];
    float sc = g2[c]*rsqrtf(v2[c] + 1e-5f);
    float sh = b2[c] - m2[c]*sc;
    __syncthreads();

    // Phase C: depthwise 3x3 SAME + BN2 + ReLU6
    float* zp = z1 + (size_t)(b*HID + c)*TR*TC;
    for (int k = tid; k < TR*TC; k += 256) {
        int r = k / TC, j = k % TC;
        float acc = 0.f;
        #pragma unroll
        for (int dr = -1; dr <= 1; ++dr)
            #pragma unroll
            for (int dj = -1; dj <= 1; ++dj) {
                int rr = r + dr, jj = j + dj;
                if (rr >= 0 && rr < TR && jj >= 0 && jj < TC)
                    acc += ffs[rr*TC + jj]*wk[(dr+1)*3 + (dj+1)];
            }
        zp[k] = relu6f(acc*sc + sh);
    }
}

// ---------------------------------------------------------------------------
// K8: 1x1 conv (192->64) + BN3 -> out. Register-tiled:
// thread = 4 px (float4) x 4 outputs; block = 16 pxg (64 px) x 16 o-chunks.
// ---------------------------------------------------------------------------
__global__ __launch_bounds__(256) void k8_conv2(
    const float* __restrict__ z1, const float* __restrict__ w2t,
    const float* __restrict__ t3, float* __restrict__ out)
{
    const int tid = threadIdx.x;
    const int pxg = tid & 15;                // 16 pixel-groups of 4
    const int oc  = tid >> 4;                // 16 o-chunks of 4
    const int pix0 = blockIdx.x*64 + pxg*4;  // 64 divides 2304 -> b uniform
    const int b   = pix0 / (TR*TC);
    const int sp  = pix0 % (TR*TC);

    float acc[4][4];                          // [px][o]
    #pragma unroll
    for (int p = 0; p < 4; ++p)
        #pragma unroll
        for (int o = 0; o < 4; ++o) acc[p][o] = 0.f;

    const float* zb = z1 + (size_t)b*HID*TR*TC + sp;
    const float* wb = w2t + oc*4;
    #pragma unroll 4
    for (int c = 0; c < HID; ++c) {
        float4 z = *(const float4*)(zb + (size_t)c*TR*TC);
        float4 w = *(const float4*)(wb + c*OUP);
        acc[0][0] += z.x*w.x; acc[0][1] += z.x*w.y; acc[0][2] += z.x*w.z; acc[0][3] += z.x*w.w;
        acc[1][0] += z.y*w.x; acc[1][1] += z.y*w.y; acc[1][2] += z.y*w.z; acc[1][3] += z.y*w.w;
        acc[2][0] += z.z*w.x; acc[2][1] += z.z*w.y; acc[2][2] += z.z*w.z; acc[2][3] += z.z*w.w;
        acc[3][0] += z.w*w.x; acc[3][1] += z.w*w.y; acc[3][2] += z.w*w.z; acc[3][3] += z.w*w.w;
    }

    const float4 tt = *(const float4*)(t3 + oc*4);
    float* ob = out + (size_t)b*OUP*TR*TC + sp;
    #pragma unroll
    for (int o = 0; o < 4; ++o) {
        float tb = (o==0)?tt.x:(o==1)?tt.y:(o==2)?tt.z:tt.w;
        float4 r = make_float4(acc[0][o]+tb, acc[1][o]+tb, acc[2][o]+tb, acc[3][o]+tb);
        *(float4*)(ob + (size_t)(oc*4 + o)*TR*TC) = r;
    }
}

// ---------------------------------------------------------------------------
extern "C" void kernel_launch(void* const* d_in, const int* in_sizes, int n_in,
                              void* d_out, int out_size, void* d_ws, size_t ws_size,
                              hipStream_t stream)
{
    const float* x    = (const float*)d_in[0];
    const float* w1   = (const float*)d_in[1];
    const float* g1   = (const float*)d_in[2];
    const float* b1   = (const float*)d_in[3];
    const float* m1   = (const float*)d_in[4];
    const float* v1   = (const float*)d_in[5];
    const float* se_w = (const float*)d_in[6];
    const float* se_b = (const float*)d_in[7];
    const float* wdw  = (const float*)d_in[8];
    const float* g2   = (const float*)d_in[9];
    const float* b2   = (const float*)d_in[10];
    const float* m2   = (const float*)d_in[11];
    const float* v2   = (const float*)d_in[12];
    const float* w2   = (const float*)d_in[13];
    const float* g3   = (const float*)d_in[14];
    const float* b3   = (const float*)d_in[15];
    const float* m3   = (const float*)d_in[16];
    const float* v3   = (const float*)d_in[17];
    float* out = (float*)d_out;

    float* ws = (float*)d_ws;
    // workspace layout (floats)
    unsigned short* y = (unsigned short*)ws;   // 28,311,552 bf16 = 14,155,776 f
    float* z1      = ws + 14155776;            //  7,077,888
    float* se6     = ws + 21233664;            //        576
    int*   iW      = (int*)(ws + 21234240);    //     73,728
    float* AW      = ws + 21307968;            //     73,728
    float* BW      = ws + 21381696;            //     73,728
    float* mm      = ws + 21455424;            //     73,728
    int*   i2T     = (int*)(ws + 21529152);    //     36,864
    float* A2T     = ws + 21566016;            //     36,864
    float* B2T     = ws + 21602880;            //     36,864
    float* se_part = ws + 21639744;            //      2,304
    float* w1s     = ws + 21642048;            //      6,144
    float* t1      = ws + 21648192;            //        192
    float* w2t     = ws + 21648384;            //     12,288
    float* t3      = ws + 21660672;            //         64

    k0_prep<<<73, 256, 0, stream>>>(w1, g1, b1, m1, v1, w2, g3, b3, m3, v3,
                                    w1s, t1, w2t, t3);
    k1_conv1<<<B_*144, 256, 0, stream>>>(x, w1s, t1, se_w, y, se_part);
    k2_se<<<3, 256, 0, stream>>>(se_part, se_b, se6);
    k3_rows<<<B_*H_, 128, 0, stream>>>(se6, iW, AW, BW, mm);
    k5_cols<<<B_*TC, 128, 0, stream>>>(mm, i2T, A2T, B2T);
    k4_warp_dw<<<B_*HID, 256, 0, stream>>>(y, iW, AW, BW, i2T, A2T, B2T,
                                           wdw, g2, b2, m2, v2, z1);
    k8_conv2<<<(B_*TR*TC)/64, 256, 0, stream>>>(z1, w2t, t3, out);
}